// Round 1
// baseline (5204.221 us; speedup 1.0000x reference)
//
#include <hip/hip_runtime.h>
#include <math.h>

#define N_EL    16
#define N_NUC   4
#define N_FEATS 32
#define N_PAIRS 184          // 64 el-nuc + 120 el-el
#define HIDDEN  64
#define G       8            // threads per batch element
#define TB      32           // batch elements per block
#define BLOCK   256
#define P_PER   (N_PAIRS / G)  // 23 pairs per thread

// triu_indices(16, 1)
__constant__ unsigned char c_I[120] = {
    0,0,0,0,0,0,0,0,0,0,0,0,0,0,0,
    1,1,1,1,1,1,1,1,1,1,1,1,1,1,
    2,2,2,2,2,2,2,2,2,2,2,2,2,
    3,3,3,3,3,3,3,3,3,3,3,3,
    4,4,4,4,4,4,4,4,4,4,4,
    5,5,5,5,5,5,5,5,5,5,
    6,6,6,6,6,6,6,6,6,
    7,7,7,7,7,7,7,7,
    8,8,8,8,8,8,8,
    9,9,9,9,9,9,
    10,10,10,10,10,
    11,11,11,11,
    12,12,12,
    13,13,
    14
};
__constant__ unsigned char c_J[120] = {
    1,2,3,4,5,6,7,8,9,10,11,12,13,14,15,
    2,3,4,5,6,7,8,9,10,11,12,13,14,15,
    3,4,5,6,7,8,9,10,11,12,13,14,15,
    4,5,6,7,8,9,10,11,12,13,14,15,
    5,6,7,8,9,10,11,12,13,14,15,
    6,7,8,9,10,11,12,13,14,15,
    7,8,9,10,11,12,13,14,15,
    8,9,10,11,12,13,14,15,
    9,10,11,12,13,14,15,
    10,11,12,13,14,15,
    11,12,13,14,15,
    12,13,14,15,
    13,14,15,
    14,15,
    15
};

// shifted softplus: softplus(x) - log(2), numerically stable form
__device__ __forceinline__ float ssp(float x) {
    float a = fabsf(x);
    return fmaxf(x, 0.0f) + log1pf(__expf(-a)) - 0.69314718056f;
}

__global__ void wfnet_kernel(const float* __restrict__ rs,
                             const float* __restrict__ coords,
                             const float* __restrict__ charges,
                             const float* __restrict__ W1,
                             const float* __restrict__ b1,
                             const float* __restrict__ W2,
                             const float* __restrict__ b2,
                             const float* __restrict__ W3,
                             const float* __restrict__ b3,
                             float* __restrict__ out)
{
    __shared__ float lds_rs[TB * N_EL * 3];   // 6 KB

    const int tid     = threadIdx.x;
    const int b_local = tid >> 3;             // 0..31
    const int g       = tid & 7;              // 0..7
    const int b       = blockIdx.x * TB + b_local;

    // stage this block's rs rows (coalesced)
    {
        const float* rs_blk = rs + (size_t)blockIdx.x * TB * N_EL * 3;
        for (int k = tid; k < TB * N_EL * 3; k += BLOCK) lds_rs[k] = rs_blk[k];
    }
    __syncthreads();

    const float* myrs = lds_rs + b_local * (N_EL * 3);

    float acc[HIDDEN];
    #pragma unroll
    for (int o = 0; o < HIDDEN; ++o) acc[o] = 0.0f;

    float asy = 0.0f;                 // partial sum of nuclear-asymptote terms
    const float decay = 1.0f;         // sqrt(2 * 0.5)

    const float4* __restrict__ W1v = (const float4*)W1;

    for (int i = 0; i < P_PER; ++i) {
        const int p = g + G * i;      // this thread's pair index
        float dx, dy, dz;
        if (p < N_EL * N_NUC) {
            const int e = p >> 2, n = p & 3;
            dx = myrs[e * 3 + 0] - coords[n * 3 + 0];
            dy = myrs[e * 3 + 1] - coords[n * 3 + 1];
            dz = myrs[e * 3 + 2] - coords[n * 3 + 2];
        } else {
            const int q  = p - N_EL * N_NUC;
            const int ei = c_I[q], ej = c_J[q];
            dx = myrs[ei * 3 + 0] - myrs[ej * 3 + 0];
            dy = myrs[ei * 3 + 1] - myrs[ej * 3 + 1];
            dz = myrs[ei * 3 + 2] - myrs[ej * 3 + 2];
        }
        const float d = sqrtf(dx * dx + dy * dy + dz * dz);

        if (p < N_EL * N_NUC) {
            const float Z = charges[p & 3];
            asy += (Z * d + decay * d * d) / (1.0f + d);
        }

        const float4* __restrict__ row = W1v + ((size_t)p << 9); // p*32 rows *16 f4

        for (int f = 0; f < N_FEATS; ++f) {
            const float qs   = (float)f * (1.0f / 31.0f);
            const float mu   = 10.0f * qs * qs;
            const float sg   = (1.0f + 10.0f * qs) * (1.0f / 7.0f);
            const float isg2 = 1.0f / (sg * sg);
            const float t    = d - mu;
            const float x    = __expf(-(t * t) * isg2);

            const float4* __restrict__ r = row + (f << 4);
            #pragma unroll
            for (int o4 = 0; o4 < 16; ++o4) {
                const float4 w = r[o4];
                acc[o4 * 4 + 0] += x * w.x;
                acc[o4 * 4 + 1] += x * w.y;
                acc[o4 * 4 + 2] += x * w.z;
                acc[o4 * 4 + 3] += x * w.w;
            }
        }
    }

    // reduce partial h1 over the 8 g-lanes (low 3 lane bits), add bias, ssp
    #pragma unroll
    for (int o = 0; o < HIDDEN; ++o) {
        float v = acc[o];
        v += __shfl_xor(v, 1);
        v += __shfl_xor(v, 2);
        v += __shfl_xor(v, 4);
        acc[o] = ssp(v + b1[o]);      // every g-lane now holds full h1[o]
    }
    asy += __shfl_xor(asy, 1);
    asy += __shfl_xor(asy, 2);
    asy += __shfl_xor(asy, 4);

    // layer 2: this lane computes outputs oo = g*8 .. g*8+7
    float a2[8];
    #pragma unroll
    for (int j = 0; j < 8; ++j) a2[j] = b2[g * 8 + j];

    const float4* __restrict__ W2v = (const float4*)W2;
    for (int k = 0; k < HIDDEN; ++k) {
        const float hk = acc[k];
        const float4 wa = W2v[k * 16 + g * 2 + 0];
        const float4 wb = W2v[k * 16 + g * 2 + 1];
        a2[0] += hk * wa.x; a2[1] += hk * wa.y;
        a2[2] += hk * wa.z; a2[3] += hk * wa.w;
        a2[4] += hk * wb.x; a2[5] += hk * wb.y;
        a2[6] += hk * wb.z; a2[7] += hk * wb.w;
    }

    // layer 3 partial dot
    float part = 0.0f;
    #pragma unroll
    for (int j = 0; j < 8; ++j) part += ssp(a2[j]) * W3[g * 8 + j];
    part += __shfl_xor(part, 1);
    part += __shfl_xor(part, 2);
    part += __shfl_xor(part, 4);

    if (g == 0) {
        const float ys = part + b3[0];
        out[b] = __expf(ys) * __expf(-asy);
    }
}

extern "C" void kernel_launch(void* const* d_in, const int* in_sizes, int n_in,
                              void* d_out, int out_size, void* d_ws, size_t ws_size,
                              hipStream_t stream) {
    const float* rs      = (const float*)d_in[0];
    const float* coords  = (const float*)d_in[1];
    const float* charges = (const float*)d_in[2];
    const float* W1      = (const float*)d_in[3];
    const float* b1      = (const float*)d_in[4];
    const float* W2      = (const float*)d_in[5];
    const float* b2      = (const float*)d_in[6];
    const float* W3      = (const float*)d_in[7];
    const float* b3      = (const float*)d_in[8];
    float* out = (float*)d_out;

    const int batch = in_sizes[0] / (N_EL * 3);   // 32768
    const int grid  = batch / TB;                 // 1024 blocks

    wfnet_kernel<<<grid, BLOCK, 0, stream>>>(rs, coords, charges,
                                             W1, b1, W2, b2, W3, b3, out);
}

// Round 2
// 5185.228 us; speedup vs baseline: 1.0037x; 1.0037x over previous
//
#include <hip/hip_runtime.h>
#include <math.h>

#define N_EL    16
#define N_NUC   4
#define N_FEATS 32
#define N_PAIRS 184          // 64 el-nuc + 120 el-el
#define HIDDEN  64
#define G       8            // threads per batch element
#define TB      32           // batch elements per block
#define BLOCK   256
#define P_PER   (N_PAIRS / G)  // 23 pairs per thread

// triu_indices(16, 1)
__constant__ unsigned char c_I[120] = {
    0,0,0,0,0,0,0,0,0,0,0,0,0,0,0,
    1,1,1,1,1,1,1,1,1,1,1,1,1,1,
    2,2,2,2,2,2,2,2,2,2,2,2,2,
    3,3,3,3,3,3,3,3,3,3,3,3,
    4,4,4,4,4,4,4,4,4,4,4,
    5,5,5,5,5,5,5,5,5,5,
    6,6,6,6,6,6,6,6,6,
    7,7,7,7,7,7,7,7,
    8,8,8,8,8,8,8,
    9,9,9,9,9,9,
    10,10,10,10,10,
    11,11,11,11,
    12,12,12,
    13,13,
    14
};
__constant__ unsigned char c_J[120] = {
    1,2,3,4,5,6,7,8,9,10,11,12,13,14,15,
    2,3,4,5,6,7,8,9,10,11,12,13,14,15,
    3,4,5,6,7,8,9,10,11,12,13,14,15,
    4,5,6,7,8,9,10,11,12,13,14,15,
    5,6,7,8,9,10,11,12,13,14,15,
    6,7,8,9,10,11,12,13,14,15,
    7,8,9,10,11,12,13,14,15,
    8,9,10,11,12,13,14,15,
    9,10,11,12,13,14,15,
    10,11,12,13,14,15,
    11,12,13,14,15,
    12,13,14,15,
    13,14,15,
    14,15,
    15
};

// shifted softplus: softplus(x) - log(2), numerically stable form
__device__ __forceinline__ float ssp(float x) {
    float a = fabsf(x);
    return fmaxf(x, 0.0f) + log1pf(__expf(-a)) - 0.69314718056f;
}

__global__ void wfnet_kernel(const float* __restrict__ rs,
                             const float* __restrict__ coords,
                             const float* __restrict__ charges,
                             const float* __restrict__ W1,
                             const float* __restrict__ b1,
                             const float* __restrict__ W2,
                             const float* __restrict__ b2,
                             const float* __restrict__ W3,
                             const float* __restrict__ b3,
                             float* __restrict__ out)
{
    __shared__ float lds_rs[TB * N_EL * 3];   // 6 KB

    const int tid     = threadIdx.x;
    const int b_local = tid >> 3;             // 0..31
    const int g       = tid & 7;              // 0..7
    const int b       = blockIdx.x * TB + b_local;

    // stage this block's rs rows (coalesced)
    {
        const float* rs_blk = rs + (size_t)blockIdx.x * TB * N_EL * 3;
        for (int k = tid; k < TB * N_EL * 3; k += BLOCK) lds_rs[k] = rs_blk[k];
    }
    __syncthreads();

    const float* myrs = lds_rs + b_local * (N_EL * 3);

    // Accumulators MUST stay in VGPRs: every access below is through
    // fully-unrolled loops (compile-time constant indices). R1 post-mortem:
    // a single runtime-indexed read (layer-2 k-loop) demoted acc[] to
    // scratch -> 5.2 ms.
    float acc[HIDDEN];
    #pragma unroll
    for (int o = 0; o < HIDDEN; ++o) acc[o] = 0.0f;

    float asy = 0.0f;                 // partial sum of nuclear-asymptote terms

    const float4* __restrict__ W1v = (const float4*)W1;

    for (int i = 0; i < P_PER; ++i) {
        const int p = g + G * i;      // this thread's pair index
        float dx, dy, dz;
        if (p < N_EL * N_NUC) {
            const int e = p >> 2, n = p & 3;
            dx = myrs[e * 3 + 0] - coords[n * 3 + 0];
            dy = myrs[e * 3 + 1] - coords[n * 3 + 1];
            dz = myrs[e * 3 + 2] - coords[n * 3 + 2];
        } else {
            const int q  = p - N_EL * N_NUC;
            const int ei = c_I[q], ej = c_J[q];
            dx = myrs[ei * 3 + 0] - myrs[ej * 3 + 0];
            dy = myrs[ei * 3 + 1] - myrs[ej * 3 + 1];
            dz = myrs[ei * 3 + 2] - myrs[ej * 3 + 2];
        }
        const float d = sqrtf(dx * dx + dy * dy + dz * dz);

        if (p < N_EL * N_NUC) {
            const float Z = charges[p & 3];
            asy += (Z * d + d * d) / (1.0f + d);   // decay = sqrt(2*0.5) = 1
        }

        const float4* __restrict__ row = W1v + ((size_t)p << 9); // p*32 rows *16 f4

        for (int f = 0; f < N_FEATS; ++f) {
            const float qs   = (float)f * (1.0f / 31.0f);
            const float mu   = 10.0f * qs * qs;
            const float sg   = (1.0f + 10.0f * qs) * (1.0f / 7.0f);
            const float isg2 = 1.0f / (sg * sg);
            const float t    = d - mu;
            const float x    = __expf(-(t * t) * isg2);

            const float4* __restrict__ r = row + (f << 4);
            #pragma unroll
            for (int o4 = 0; o4 < 16; ++o4) {
                const float4 w = r[o4];
                acc[o4 * 4 + 0] += x * w.x;
                acc[o4 * 4 + 1] += x * w.y;
                acc[o4 * 4 + 2] += x * w.z;
                acc[o4 * 4 + 3] += x * w.w;
            }
        }
    }

    // reduce partial h1 over the 8 g-lanes (low 3 lane bits), add bias, ssp
    #pragma unroll
    for (int o = 0; o < HIDDEN; ++o) {
        float v = acc[o];
        v += __shfl_xor(v, 1);
        v += __shfl_xor(v, 2);
        v += __shfl_xor(v, 4);
        acc[o] = ssp(v + b1[o]);      // every g-lane now holds full h1[o]
    }
    asy += __shfl_xor(asy, 1);
    asy += __shfl_xor(asy, 2);
    asy += __shfl_xor(asy, 4);

    // layer 2: this lane computes outputs oo = g*8 .. g*8+7
    float a2[8];
    #pragma unroll
    for (int j = 0; j < 8; ++j) a2[j] = b2[g * 8 + j];

    const float4* __restrict__ W2v = (const float4*)W2;
    #pragma unroll   // MUST unroll: acc[k] needs a constant index (see R1)
    for (int k = 0; k < HIDDEN; ++k) {
        const float hk = acc[k];
        const float4 wa = W2v[k * 16 + g * 2 + 0];
        const float4 wb = W2v[k * 16 + g * 2 + 1];
        a2[0] += hk * wa.x; a2[1] += hk * wa.y;
        a2[2] += hk * wa.z; a2[3] += hk * wa.w;
        a2[4] += hk * wb.x; a2[5] += hk * wb.y;
        a2[6] += hk * wb.z; a2[7] += hk * wb.w;
    }

    // layer 3 partial dot
    float part = 0.0f;
    #pragma unroll
    for (int j = 0; j < 8; ++j) part += ssp(a2[j]) * W3[g * 8 + j];
    part += __shfl_xor(part, 1);
    part += __shfl_xor(part, 2);
    part += __shfl_xor(part, 4);

    if (g == 0) {
        const float ys = part + b3[0];
        out[b] = __expf(ys) * __expf(-asy);
    }
}

extern "C" void kernel_launch(void* const* d_in, const int* in_sizes, int n_in,
                              void* d_out, int out_size, void* d_ws, size_t ws_size,
                              hipStream_t stream) {
    const float* rs      = (const float*)d_in[0];
    const float* coords  = (const float*)d_in[1];
    const float* charges = (const float*)d_in[2];
    const float* W1      = (const float*)d_in[3];
    const float* b1      = (const float*)d_in[4];
    const float* W2      = (const float*)d_in[5];
    const float* b2      = (const float*)d_in[6];
    const float* W3      = (const float*)d_in[7];
    const float* b3      = (const float*)d_in[8];
    float* out = (float*)d_out;

    const int batch = in_sizes[0] / (N_EL * 3);   // 32768
    const int grid  = batch / TB;                 // 1024 blocks

    wfnet_kernel<<<grid, BLOCK, 0, stream>>>(rs, coords, charges,
                                             W1, b1, W2, b2, W3, b3, out);
}